// Round 5
// baseline (100.151 us; speedup 1.0000x reference)
//
#include <hip/hip_runtime.h>
#include <math.h>

#define NQ   4
#define NH   8
#define NL   2
#define DIM  16   // 2^NQ
#define EMB  32
#define TPB  64   // tokens per block
#define EVP  33   // evs[t][k] pad: bank (t+k)%32 -> max 2-way (free)
#define EHS  328  // per-head stride of E (324 coeffs + pad, 16B-aligned)

// Constant-address-space alias: wave-uniform loads through this pointer
// compile to s_load (SMEM pipe, SGPR result).
using cfloat = const __attribute__((address_space(4))) float;
__device__ __forceinline__ cfloat* cptr(const float* p) {
    return (cfloat*)(unsigned long long)p;
}

// ---------------------------------------------------------------------------
// Setup 1: per-head 16x16 unitary (2 layers RX/RY/RZ + CNOT ring).
// 128 threads = (head, column). Fully unrolled, static register indices.
// Uws layout: Ur[h][m][j] at ws[(h*16+m)*16+j], Ui at ws+2048.
// ---------------------------------------------------------------------------
__global__ void build_unitaries_kernel(const float* __restrict__ params,
                                       float* __restrict__ Uws) {
    int tid = threadIdx.x;          // 0..127
    int h   = tid >> 4;
    int col = tid & 15;

    float re[DIM], im[DIM];
#pragma unroll
    for (int j = 0; j < DIM; ++j) { re[j] = (j == col) ? 1.f : 0.f; im[j] = 0.f; }

#pragma unroll
    for (int l = 0; l < NL; ++l) {
#pragma unroll
        for (int q = 0; q < NQ; ++q) {
            const float* p = params + ((h * NL + l) * NQ + q) * 3;
            const int m = 1 << (3 - q);
            {   // RX
                float s, c; __sincosf(0.5f * p[0], &s, &c);
#pragma unroll
                for (int j = 0; j < DIM; ++j) {
                    if (j & m) continue;
                    const int j1 = j | m;
                    float r0 = re[j], i0 = im[j], r1 = re[j1], i1 = im[j1];
                    re[j]  = c * r0 + s * i1;
                    im[j]  = c * i0 - s * r1;
                    re[j1] = s * i0 + c * r1;
                    im[j1] = -s * r0 + c * i1;
                }
            }
            {   // RY
                float s, c; __sincosf(0.5f * p[1], &s, &c);
#pragma unroll
                for (int j = 0; j < DIM; ++j) {
                    if (j & m) continue;
                    const int j1 = j | m;
                    float r0 = re[j], i0 = im[j], r1 = re[j1], i1 = im[j1];
                    re[j]  = c * r0 - s * r1;
                    im[j]  = c * i0 - s * i1;
                    re[j1] = s * r0 + c * r1;
                    im[j1] = s * i0 + c * i1;
                }
            }
            {   // RZ
                float s, c; __sincosf(0.5f * p[2], &s, &c);
#pragma unroll
                for (int j = 0; j < DIM; ++j) {
                    if (j & m) continue;
                    const int j1 = j | m;
                    float r0 = re[j], i0 = im[j], r1 = re[j1], i1 = im[j1];
                    re[j]  = c * r0 + s * i0;
                    im[j]  = c * i0 - s * r0;
                    re[j1] = c * r1 - s * i1;
                    im[j1] = c * i1 + s * r1;
                }
            }
        }
#pragma unroll
        for (int e = 0; e < NQ; ++e) {   // CNOT ring
            const int cm = 1 << (3 - e), tm = 1 << (3 - ((e + 1) & 3));
#pragma unroll
            for (int j = 0; j < DIM; ++j) {
                if ((j & cm) && !(j & tm)) {
                    const int j1 = j | tm;
                    float tr = re[j]; re[j] = re[j1]; re[j1] = tr;
                    float ti = im[j]; im[j] = im[j1]; im[j1] = ti;
                }
            }
        }
    }
#pragma unroll
    for (int j = 0; j < DIM; ++j) {
        Uws[(h * DIM + j) * DIM + col]        = re[j];
        Uws[2048 + (h * DIM + j) * DIM + col] = im[j];
    }
}

// ---------------------------------------------------------------------------
// Setup 2: monomial coefficient tensor E[h][q][a][b] (4x9x9 per head):
//   ev_q = sum_{a,b} E[q][a][b] * m01[a] * m23[b],
// where m01 = (1,C0,S0)x(1,C1,S1), m23 = (1,C2,S2)x(1,C3,S3), C=cos(x),
// S=sin(x) (FULL angle; double-angle identities absorbed into E).
// Derivation: ev_q = psi^T A_q psi, A_q = Re(U^dag Z_q U); per-qubit factors
// cc=(1+C)/2, ss=(1-C)/2, cs=S/2 expand each (j,k) entry into 16 monomials.
// Per (a,b): sum over 16 (j,k) pairs (2 options/qubit) with signs:
//   t=1 (const): (o,o,+) ; t=C: (o,o, o?-:+) ; t=S: (o,1-o,+).
// Grid: 8 blocks (head) x 384 threads (q*81+a*9+b < 324 active). One-off.
// ---------------------------------------------------------------------------
__global__ void build_E_kernel(const float* __restrict__ Uws,
                               float* __restrict__ Ews) {
    const int h   = blockIdx.x;
    const int tid = threadIdx.x;
    __shared__ float Urs[256], Uis[256];
    if (tid < 256) {
        Urs[tid] = Uws[h * 256 + tid];
        Uis[tid] = Uws[2048 + h * 256 + tid];
    }
    __syncthreads();
    if (tid >= 324) return;

    const int q  = tid / 81;
    const int ab = tid % 81;
    const int a = ab / 9, b = ab % 9;
    const int t0 = a / 3, t1 = a % 3, t2 = b / 3, t3 = b % 3;

    float Sv[16];
#pragma unroll
    for (int m = 0; m < 16; ++m) Sv[m] = 0.f;

    for (int c = 0; c < 16; ++c) {
        const int o0 = (c >> 3) & 1, o1 = (c >> 2) & 1;
        const int o2 = (c >> 1) & 1, o3 = c & 1;
        float sg = 1.f;
        const int bk0 = (t0 == 2) ? (1 - o0) : o0; if (t0 == 1 && o0) sg = -sg;
        const int bk1 = (t1 == 2) ? (1 - o1) : o1; if (t1 == 1 && o1) sg = -sg;
        const int bk2 = (t2 == 2) ? (1 - o2) : o2; if (t2 == 1 && o2) sg = -sg;
        const int bk3 = (t3 == 2) ? (1 - o3) : o3; if (t3 == 1 && o3) sg = -sg;
        const int j = (o0 << 3) | (o1 << 2) | (o2 << 1) | o3;
        const int k = (bk0 << 3) | (bk1 << 2) | (bk2 << 1) | bk3;
#pragma unroll
        for (int m = 0; m < 16; ++m) {
            const float v = Urs[m * 16 + j] * Urs[m * 16 + k]
                          + Uis[m * 16 + j] * Uis[m * 16 + k];
            Sv[m] = fmaf(sg, v, Sv[m]);
        }
    }
    float acc = 0.f;
#pragma unroll
    for (int m = 0; m < 16; ++m)
        acc += ((m >> (3 - q)) & 1) ? -Sv[m] : Sv[m];

    Ews[h * EHS + tid] = acc * 0.0625f;   // /16
}

// ---------------------------------------------------------------------------
// Main: block = 512 threads = 8 waves, 64 tokens, no guards (exact grid).
// Phase 1: wave = head, lane = token. 4 full-angle sincos -> 18 monomial
// half-products -> ev_q = sum_a m01[a]*(sum_b E[q][a][b]*m23[b]): 360 FMA in
// 36 independent 9-chains (vs 512 FMA/16-deep chains of the matvec form).
// E via AS(4) wave-uniform s_loads. evs[t][k] pad 33 (2-way banks, free).
// Phase 2: wave = output quad e=4w..4w+3 (W,b wave-uniform s_loads),
// lane = token; float4 stores, block's 8 waves fill each 128B line.
// ---------------------------------------------------------------------------
__global__ __launch_bounds__(512, 4)
void qmha_kernel(const float* __restrict__ x,
                 const float* __restrict__ Ews,
                 const float* __restrict__ W,
                 const float* __restrict__ bvec,
                 float* __restrict__ out) {
    __shared__ float evs[TPB * EVP];   // evs[t][k], k = h*4+q

    const int tid  = threadIdx.x;
    const int tok0 = blockIdx.x * TPB;
    const int lane = tid & 63;

    // ---- phase 1 ----
    {
        const int h = __builtin_amdgcn_readfirstlane(tid >> 6);
        const int tok = tok0 + lane;

        const float4 xa = *(const float4*)(x + (size_t)tok * EMB + h * NQ);
        float C0, S0, C1, S1, C2, S2, C3, S3;
        __sincosf(xa.x, &S0, &C0);
        __sincosf(xa.y, &S1, &C1);
        __sincosf(xa.z, &S2, &C2);
        __sincosf(xa.w, &S3, &C3);

        float m01[9], m23[9];
        m01[0] = 1.f; m01[1] = C1;      m01[2] = S1;
        m01[3] = C0;  m01[4] = C0 * C1; m01[5] = C0 * S1;
        m01[6] = S0;  m01[7] = S0 * C1; m01[8] = S0 * S1;
        m23[0] = 1.f; m23[1] = C3;      m23[2] = S3;
        m23[3] = C2;  m23[4] = C2 * C3; m23[5] = C2 * S3;
        m23[6] = S2;  m23[7] = S2 * C3; m23[8] = S2 * S3;

        cfloat* E = cptr(Ews + h * EHS);

#pragma unroll
        for (int q = 0; q < NQ; ++q) {
            float acc = 0.f;
#pragma unroll
            for (int a = 0; a < 9; ++a) {
                float inner = 0.f;
#pragma unroll
                for (int b = 0; b < 9; ++b)
                    inner = fmaf(E[q * 81 + a * 9 + b], m23[b], inner);
                acc = fmaf(m01[a], inner, acc);
            }
            evs[lane * EVP + h * 4 + q] = acc;
        }
    }
    __syncthreads();

    // ---- phase 2: out[tok][e] = b[e] + sum_k ev[tok][k] * W[e][k] ----
    {
        const int w  = __builtin_amdgcn_readfirstlane(tid >> 6);
        const int e0 = w * 4;

        cfloat* Wr = cptr(W);
        cfloat* bc = cptr(bvec);

        float o0 = bc[e0 + 0], o1 = bc[e0 + 1], o2 = bc[e0 + 2], o3 = bc[e0 + 3];
#pragma unroll
        for (int k = 0; k < EMB; ++k) {
            const float evk = evs[lane * EVP + k];
            o0 = fmaf(Wr[(e0 + 0) * EMB + k], evk, o0);
            o1 = fmaf(Wr[(e0 + 1) * EMB + k], evk, o1);
            o2 = fmaf(Wr[(e0 + 2) * EMB + k], evk, o2);
            o3 = fmaf(Wr[(e0 + 3) * EMB + k], evk, o3);
        }
        float4 v; v.x = o0; v.y = o1; v.z = o2; v.w = o3;
        *(float4*)(out + (size_t)(tok0 + lane) * EMB + e0) = v;
    }
}

extern "C" void kernel_launch(void* const* d_in, const int* in_sizes, int n_in,
                              void* d_out, int out_size, void* d_ws, size_t ws_size,
                              hipStream_t stream) {
    const float* x      = (const float*)d_in[0];
    const float* params = (const float*)d_in[1];
    const float* W_out  = (const float*)d_in[2];
    const float* b_out  = (const float*)d_in[3];
    float*       out    = (float*)d_out;
    float*       Uws    = (float*)d_ws;            // 4096 floats
    float*       Ews    = (float*)d_ws + 4096;     // 8*328 floats

    const int ntok = in_sizes[0] / EMB;   // B*S = 131072, divisible by TPB

    hipLaunchKernelGGL(build_unitaries_kernel, dim3(1), dim3(128), 0, stream,
                       params, Uws);
    hipLaunchKernelGGL(build_E_kernel, dim3(NH), dim3(384), 0, stream,
                       Uws, Ews);
    hipLaunchKernelGGL(qmha_kernel, dim3(ntok / TPB), dim3(512), 0, stream,
                       x, Ews, W_out, b_out, out);
}

// Round 6
// 96.678 us; speedup vs baseline: 1.0359x; 1.0359x over previous
//
#include <hip/hip_runtime.h>
#include <math.h>

#define NQ   4
#define NH   8
#define NL   2
#define DIM  16   // 2^NQ
#define EMB  32
#define TPB  64   // tokens per block
#define EVP  34   // evs[t][k] pad (even -> 8B-aligned b64; banks 2t+k, <=4-way)
#define EH   324  // floats per head in Eq4 (81 ab * 4 q); 1296 B, 16B-aligned
#define WPK_OFF (NH * EH)   // float offset of packed W (16 pairs x 32 k x 2)

typedef float v2f __attribute__((ext_vector_type(2)));
typedef float v4f __attribute__((ext_vector_type(4)));

// ---------------------------------------------------------------------------
// ONE setup kernel, 8 blocks (= head) x 384 threads:
//   tid 0..15   : build column tid of U_h (2 layers RX/RY/RZ + CNOT ring),
//                 fully unrolled, static register indices -> LDS Urs/Uis.
//   tid 64..127 : (independent, pre-barrier) pack W into pair-interleaved
//                 Wpk[ep][k] = {W[2ep][k], W[2ep+1][k]}, block h does
//                 ep = 2h, 2h+1.
//   barrier
//   tid 0..323  : E coefficients (round-5 verified math), NEW layout
//                 ws[h*324 + (a*9+b)*4 + q]  -> float4 per (a,b) over q.
// ---------------------------------------------------------------------------
__global__ void setup_kernel(const float* __restrict__ params,
                             const float* __restrict__ W,
                             float* __restrict__ ws) {
    __shared__ float Urs[256], Uis[256];
    const int h   = blockIdx.x;
    const int tid = threadIdx.x;

    if (tid < 16) {
        const int col = tid;
        float re[DIM], im[DIM];
#pragma unroll
        for (int j = 0; j < DIM; ++j) { re[j] = (j == col) ? 1.f : 0.f; im[j] = 0.f; }

#pragma unroll
        for (int l = 0; l < NL; ++l) {
#pragma unroll
            for (int q = 0; q < NQ; ++q) {
                const float* p = params + ((h * NL + l) * NQ + q) * 3;
                const int m = 1 << (3 - q);
                {   // RX
                    float s, c; __sincosf(0.5f * p[0], &s, &c);
#pragma unroll
                    for (int j = 0; j < DIM; ++j) {
                        if (j & m) continue;
                        const int j1 = j | m;
                        float r0 = re[j], i0 = im[j], r1 = re[j1], i1 = im[j1];
                        re[j]  = c * r0 + s * i1;
                        im[j]  = c * i0 - s * r1;
                        re[j1] = s * i0 + c * r1;
                        im[j1] = -s * r0 + c * i1;
                    }
                }
                {   // RY
                    float s, c; __sincosf(0.5f * p[1], &s, &c);
#pragma unroll
                    for (int j = 0; j < DIM; ++j) {
                        if (j & m) continue;
                        const int j1 = j | m;
                        float r0 = re[j], i0 = im[j], r1 = re[j1], i1 = im[j1];
                        re[j]  = c * r0 - s * r1;
                        im[j]  = c * i0 - s * i1;
                        re[j1] = s * r0 + c * r1;
                        im[j1] = s * i0 + c * i1;
                    }
                }
                {   // RZ
                    float s, c; __sincosf(0.5f * p[2], &s, &c);
#pragma unroll
                    for (int j = 0; j < DIM; ++j) {
                        if (j & m) continue;
                        const int j1 = j | m;
                        float r0 = re[j], i0 = im[j], r1 = re[j1], i1 = im[j1];
                        re[j]  = c * r0 + s * i0;
                        im[j]  = c * i0 - s * r0;
                        re[j1] = c * r1 - s * i1;
                        im[j1] = c * i1 + s * r1;
                    }
                }
            }
#pragma unroll
            for (int e = 0; e < NQ; ++e) {   // CNOT ring
                const int cm = 1 << (3 - e), tm = 1 << (3 - ((e + 1) & 3));
#pragma unroll
                for (int j = 0; j < DIM; ++j) {
                    if ((j & cm) && !(j & tm)) {
                        const int j1 = j | tm;
                        float tr = re[j]; re[j] = re[j1]; re[j1] = tr;
                        float ti = im[j]; im[j] = im[j1]; im[j1] = ti;
                    }
                }
            }
        }
#pragma unroll
        for (int j = 0; j < DIM; ++j) {
            Urs[j * 16 + col] = re[j];
            Uis[j * 16 + col] = im[j];
        }
    } else if (tid >= 64 && tid < 128) {
        // pack W pairs (independent of U)
        const int i  = tid - 64;          // 0..63
        const int ep = 2 * h + (i >> 5);  // this block's two output pairs
        const int k  = i & 31;
        float2 v;
        v.x = W[(2 * ep) * EMB + k];
        v.y = W[(2 * ep + 1) * EMB + k];
        *(float2*)(ws + WPK_OFF + (ep * EMB + k) * 2) = v;
    }
    __syncthreads();

    if (tid >= 324) return;

    // ---- E coefficients: ev_q = sum_{a,b} E[q][a][b] m01[a] m23[b] ----
    const int q  = tid / 81;
    const int ab = tid % 81;
    const int a = ab / 9, b = ab % 9;
    const int t0 = a / 3, t1 = a % 3, t2 = b / 3, t3 = b % 3;

    float Sv[16];
#pragma unroll
    for (int m = 0; m < 16; ++m) Sv[m] = 0.f;

    for (int c = 0; c < 16; ++c) {
        const int o0 = (c >> 3) & 1, o1 = (c >> 2) & 1;
        const int o2 = (c >> 1) & 1, o3 = c & 1;
        float sg = 1.f;
        const int bk0 = (t0 == 2) ? (1 - o0) : o0; if (t0 == 1 && o0) sg = -sg;
        const int bk1 = (t1 == 2) ? (1 - o1) : o1; if (t1 == 1 && o1) sg = -sg;
        const int bk2 = (t2 == 2) ? (1 - o2) : o2; if (t2 == 1 && o2) sg = -sg;
        const int bk3 = (t3 == 2) ? (1 - o3) : o3; if (t3 == 1 && o3) sg = -sg;
        const int j = (o0 << 3) | (o1 << 2) | (o2 << 1) | o3;
        const int k = (bk0 << 3) | (bk1 << 2) | (bk2 << 1) | bk3;
#pragma unroll
        for (int m = 0; m < 16; ++m) {
            const float v = Urs[m * 16 + j] * Urs[m * 16 + k]
                          + Uis[m * 16 + j] * Uis[m * 16 + k];
            Sv[m] = fmaf(sg, v, Sv[m]);
        }
    }
    float acc = 0.f;
#pragma unroll
    for (int m = 0; m < 16; ++m)
        acc += ((m >> (3 - q)) & 1) ? -Sv[m] : Sv[m];

    ws[h * EH + ab * 4 + q] = acc * 0.0625f;   // /16
}

// ---------------------------------------------------------------------------
// Main: block = 512 threads = 8 waves, 64 tokens, exact grid (no guards),
// entire 2048-block grid co-resident (8 blocks/CU, VGPR kept low).
// Phase 1: wave = head, lane = token. 4 full-angle sincos -> 18 monomial
// products -> packed-fp32 polynomial: per (a,b) one float4 E load (per-lane
// VMEM, same addr across lanes -> L1 broadcast, deep vmcnt pipelining) +
// 2 v_pk_fma_f32 -> (ev0,ev1),(ev2,ev3): 180 packed FMA vs 360 scalar.
// Phase 2: wave = output quad e=4w..4w+3; W pre-paired -> float4 loads,
// evs pairs via 8B LDS reads, 64 packed FMA; contiguous float4 store.
// ---------------------------------------------------------------------------
__global__ __launch_bounds__(512)
void qmha_kernel(const float* __restrict__ x,
                 const float* __restrict__ ws,
                 const float* __restrict__ bvec,
                 float* __restrict__ out) {
    __shared__ float evs[TPB * EVP];   // evs[t][k], k = h*4+q

    const int tid  = threadIdx.x;
    const int tok0 = blockIdx.x * TPB;
    const int lane = tid & 63;

    // ---- phase 1 ----
    {
        const int h = __builtin_amdgcn_readfirstlane(tid >> 6);
        const int tok = tok0 + lane;

        const float4 xa = *(const float4*)(x + (size_t)tok * EMB + h * NQ);
        float C0, S0, C1, S1, C2, S2, C3, S3;
        __sincosf(xa.x, &S0, &C0);
        __sincosf(xa.y, &S1, &C1);
        __sincosf(xa.z, &S2, &C2);
        __sincosf(xa.w, &S3, &C3);

        float m01[9], m23[9];
        m01[0] = 1.f; m01[1] = C1;      m01[2] = S1;
        m01[3] = C0;  m01[4] = C0 * C1; m01[5] = C0 * S1;
        m01[6] = S0;  m01[7] = S0 * C1; m01[8] = S0 * S1;
        m23[0] = 1.f; m23[1] = C3;      m23[2] = S3;
        m23[3] = C2;  m23[4] = C2 * C3; m23[5] = C2 * S3;
        m23[6] = S2;  m23[7] = S2 * C3; m23[8] = S2 * S3;

        const v4f* __restrict__ E4 = (const v4f*)(ws + h * EH);

        v2f ev01 = {0.f, 0.f}, ev23 = {0.f, 0.f};
#pragma unroll
        for (int a = 0; a < 9; ++a) {
            v2f i01 = {0.f, 0.f}, i23 = {0.f, 0.f};
#pragma unroll
            for (int b = 0; b < 9; ++b) {
                const v4f e = E4[a * 9 + b];
                const v2f mb = {m23[b], m23[b]};
                i01 = __builtin_elementwise_fma(__builtin_shufflevector(e, e, 0, 1), mb, i01);
                i23 = __builtin_elementwise_fma(__builtin_shufflevector(e, e, 2, 3), mb, i23);
            }
            const v2f ma = {m01[a], m01[a]};
            ev01 = __builtin_elementwise_fma(ma, i01, ev01);
            ev23 = __builtin_elementwise_fma(ma, i23, ev23);
        }

        evs[lane * EVP + h * 4 + 0] = ev01.x;
        evs[lane * EVP + h * 4 + 1] = ev01.y;
        evs[lane * EVP + h * 4 + 2] = ev23.x;
        evs[lane * EVP + h * 4 + 3] = ev23.y;
    }
    __syncthreads();

    // ---- phase 2: out[tok][e0..e0+3], packed over output pairs ----
    {
        const int w   = __builtin_amdgcn_readfirstlane(tid >> 6);
        const int e0  = w * 4;
        const int ep0 = w * 2;

        const v4f* __restrict__ Wp0 = (const v4f*)(ws + WPK_OFF + (ep0 + 0) * 64);
        const v4f* __restrict__ Wp1 = (const v4f*)(ws + WPK_OFF + (ep0 + 1) * 64);

        v2f o01 = {bvec[e0 + 0], bvec[e0 + 1]};
        v2f o23 = {bvec[e0 + 2], bvec[e0 + 3]};
#pragma unroll
        for (int kk = 0; kk < 16; ++kk) {
            const v4f A = Wp0[kk];   // {W[e0][2kk],W[e0+1][2kk],W[e0][2kk+1],W[e0+1][2kk+1]}
            const v4f B = Wp1[kk];
            const v2f ev2 = *(const v2f*)(evs + lane * EVP + 2 * kk);
            const v2f ek0 = {ev2.x, ev2.x};
            const v2f ek1 = {ev2.y, ev2.y};
            o01 = __builtin_elementwise_fma(__builtin_shufflevector(A, A, 0, 1), ek0, o01);
            o01 = __builtin_elementwise_fma(__builtin_shufflevector(A, A, 2, 3), ek1, o01);
            o23 = __builtin_elementwise_fma(__builtin_shufflevector(B, B, 0, 1), ek0, o23);
            o23 = __builtin_elementwise_fma(__builtin_shufflevector(B, B, 2, 3), ek1, o23);
        }
        v4f v = {o01.x, o01.y, o23.x, o23.y};
        *(v4f*)(out + (size_t)(tok0 + lane) * EMB + e0) = v;
    }
}

extern "C" void kernel_launch(void* const* d_in, const int* in_sizes, int n_in,
                              void* d_out, int out_size, void* d_ws, size_t ws_size,
                              hipStream_t stream) {
    const float* x      = (const float*)d_in[0];
    const float* params = (const float*)d_in[1];
    const float* W_out  = (const float*)d_in[2];
    const float* b_out  = (const float*)d_in[3];
    float*       out    = (float*)d_out;
    float*       ws     = (float*)d_ws;   // E: 8*324 floats, Wpk: 1024 floats

    const int ntok = in_sizes[0] / EMB;   // B*S = 131072, divisible by TPB

    hipLaunchKernelGGL(setup_kernel, dim3(NH), dim3(384), 0, stream,
                       params, W_out, ws);
    hipLaunchKernelGGL(qmha_kernel, dim3(ntok / TPB), dim3(512), 0, stream,
                       x, ws, b_out, out);
}